// Round 1
// baseline (274.993 us; speedup 1.0000x reference)
//
#include <hip/hip_runtime.h>
#include <hip/hip_bf16.h>
#include <cstdint>

typedef __bf16 bf16;
typedef __attribute__((ext_vector_type(8))) __bf16 bf16x8;
typedef __attribute__((ext_vector_type(4))) __bf16 bf16x4;
typedef __attribute__((ext_vector_type(4))) float f32x4;

#define MFMA16 __builtin_amdgcn_mfma_f32_16x16x32_bf16
#define MASKV (-1e30f)

static constexpr int Lq  = 2048;
static constexpr int BQ  = 64;    // q rows per workgroup (16 per wave)
static constexpr int BKt = 128;   // keys per tile
static constexpr int TW  = 146;   // T-window stride (144 cols + pad for bank spread)

__device__ __forceinline__ void async_load16(const void* g, void* l) {
  __builtin_amdgcn_global_load_lds(
      (__attribute__((address_space(1))) void*)g,
      (__attribute__((address_space(3))) void*)l, 16, 0, 0);
}

// ---------------------------------------------------------------------------
// fp32 -> bf16 conversion of all inputs (E kept unflipped; flip applied at use)
// ---------------------------------------------------------------------------
__global__ void convert_all(const float* __restrict__ q, const float* __restrict__ k,
                            const float* __restrict__ v, const float* __restrict__ wq,
                            const float* __restrict__ wk, const float* __restrict__ wv,
                            const float* __restrict__ fc, const float* __restrict__ E,
                            bf16* q_bf, bf16* k_bf, bf16* v_bf, bf16* wq_bf,
                            bf16* wk_bf, bf16* wv_bf, bf16* fc_bf, bf16* E_bf)
{
  int i = blockIdx.x * blockDim.x + threadIdx.x;   // vec4 index
  const float* src; bf16* dst; int rel;
  if      (i < 524288)  { src = q;  dst = q_bf;  rel = i; }
  else if (i < 1048576) { src = k;  dst = k_bf;  rel = i - 524288; }
  else if (i < 1572864) { src = v;  dst = v_bf;  rel = i - 1048576; }
  else if (i < 1638400) { src = wq; dst = wq_bf; rel = i - 1572864; }
  else if (i < 1703936) { src = wk; dst = wk_bf; rel = i - 1638400; }
  else if (i < 1769472) { src = wv; dst = wv_bf; rel = i - 1703936; }
  else if (i < 1835008) { src = fc; dst = fc_bf; rel = i - 1769472; }
  else if (i < 1867776) { src = E;  dst = E_bf;  rel = i - 1835008; }
  else return;
  float4 x = *(const float4*)(src + (size_t)rel * 4);
  bf16x4 o;
  o[0] = (bf16)x.x; o[1] = (bf16)x.y; o[2] = (bf16)x.z; o[3] = (bf16)x.w;
  *(bf16x4*)(dst + (size_t)rel * 4) = o;
}

// ---------------------------------------------------------------------------
// Generic 128x128-tile bf16 GEMM, C[i][j] = sum_k A[i][k]*B[j][k] + bias
// K = 512 fixed, lda = ldb = 512.
// MODE 0: C bf16 in (B,H,L,DH) layout (i=b*2048+l, j=h*64+dh)   [q_h / k_h]
// MODE 2: C bf16 in (B,H,DH,L) layout (i=h*64+dh, j=b*2048+l)   [v^T], bias[i]
// MODE 3: C fp32 row-major (4096 x 512)                          [final out]
// ---------------------------------------------------------------------------
template<int MODE>
__global__ __launch_bounds__(256, 2)
void gemm512(const bf16* __restrict__ A, const bf16* __restrict__ Bm,
             const float* __restrict__ bias, void* __restrict__ Cv)
{
  __shared__ __align__(16) char lA[16384];
  __shared__ __align__(16) char lB[16384];
  const int tid = threadIdx.x, lane = tid & 63, wv = tid >> 6;
  const int wr = wv >> 1, wc = wv & 1;
  const int tm = blockIdx.x, tn = blockIdx.y;

  f32x4 acc[4][4];
#pragma unroll
  for (int m = 0; m < 4; ++m)
#pragma unroll
    for (int n = 0; n < 4; ++n) acc[m][n] = (f32x4){0.f, 0.f, 0.f, 0.f};

  for (int k0 = 0; k0 < 512; k0 += 64) {
    __syncthreads();
#pragma unroll
    for (int it = 0; it < 4; ++it) {
      int slot = it * 256 + wv * 64 + lane;
      int row = slot >> 3, c = slot & 7;
      int gk = k0 + ((c ^ (row & 7)) * 8);
      async_load16(A  + (size_t)(tm * 128 + row) * 512 + gk, lA + (it * 256 + wv * 64) * 16);
      async_load16(Bm + (size_t)(tn * 128 + row) * 512 + gk, lB + (it * 256 + wv * 64) * 16);
    }
    __syncthreads();
#pragma unroll
    for (int kc = 0; kc < 2; ++kc) {
      bf16x8 af[4], bfr[4];
#pragma unroll
      for (int m = 0; m < 4; ++m) {
        int row = wr * 64 + m * 16 + (lane & 15);
        int ch = ((lane >> 4) + kc * 4) ^ (row & 7);
        af[m] = *(const bf16x8*)(lA + row * 128 + ch * 16);
      }
#pragma unroll
      for (int n = 0; n < 4; ++n) {
        int row = wc * 64 + n * 16 + (lane & 15);
        int ch = ((lane >> 4) + kc * 4) ^ (row & 7);
        bfr[n] = *(const bf16x8*)(lB + row * 128 + ch * 16);
      }
#pragma unroll
      for (int m = 0; m < 4; ++m)
#pragma unroll
        for (int n = 0; n < 4; ++n)
          acc[m][n] = MFMA16(af[m], bfr[n], acc[m][n], 0, 0, 0);
    }
  }

#pragma unroll
  for (int m = 0; m < 4; ++m)
#pragma unroll
    for (int n = 0; n < 4; ++n)
#pragma unroll
      for (int r = 0; r < 4; ++r) {
        int gi = tm * 128 + wr * 64 + m * 16 + 4 * (lane >> 4) + r;
        int gj = tn * 128 + wc * 64 + n * 16 + (lane & 15);
        float vv = acc[m][n][r] + ((MODE == 2) ? bias[gi] : bias[gj]);
        if (MODE == 3) {
          ((float*)Cv)[(size_t)gi * 512 + gj] = vv;
        } else if (MODE == 2) {
          int h = gi >> 6, dh = gi & 63, b = gj >> 11, l = gj & 2047;
          ((bf16*)Cv)[((size_t)((b * 8 + h) * 64 + dh)) * 2048 + l] = (bf16)vv;
        } else {
          int b = gi >> 11, l = gi & 2047, h = gj >> 6, dh = gj & 63;
          ((bf16*)Cv)[((size_t)((b * 8 + h) * 2048 + l)) * 64 + dh] = (bf16)vv;
        }
      }
}

// ---------------------------------------------------------------------------
// Attention: computes masked logits tile into acc_s (scaled by 1/8, masked
// entries = MASKV). lds_k must be staged. T strip (per-wave) used as scratch.
// Srel[i][j] = q_h[i] . E[2047-(i-j)]  (window r in [rbase, rbase+143])
// ---------------------------------------------------------------------------
__device__ __forceinline__ void attn_logits(
    int i0, int j0, int wv, int lane,
    const bf16x8 qf0, const bf16x8 qf1,
    const bf16* __restrict__ Ebf,
    const char* lds_k, float* tst, f32x4 acc_s[8])
{
  const int rbase = i0 + wv * 16 - j0 - 127;
  f32x4 acc_t[9];
#pragma unroll
  for (int cf = 0; cf < 9; ++cf) {
    f32x4 a = (f32x4){0.f, 0.f, 0.f, 0.f};
    int r = rbase + cf * 16 + (lane & 15);
    int re = 2047 - r; re = re < 0 ? 0 : (re > 2047 ? 2047 : re);
    const bf16* ep = Ebf + re * 64 + (lane >> 4) * 8;
    a = MFMA16(qf0, *(const bf16x8*)ep, a, 0, 0, 0);
    a = MFMA16(qf1, *(const bf16x8*)(ep + 32), a, 0, 0, 0);
    acc_t[cf] = a;
  }
#pragma unroll
  for (int cf = 0; cf < 9; ++cf)
#pragma unroll
    for (int r = 0; r < 4; ++r)
      tst[(4 * (lane >> 4) + r) * TW + cf * 16 + (lane & 15)] = acc_t[cf][r];
  asm volatile("s_waitcnt lgkmcnt(0)" ::: "memory");

#pragma unroll
  for (int cf = 0; cf < 8; ++cf) {
    f32x4 a = (f32x4){0.f, 0.f, 0.f, 0.f};
    int key = cf * 16 + (lane & 15);
    int c0 = (lane >> 4) ^ (key & 7);
    int c1 = ((lane >> 4) + 4) ^ (key & 7);
    a = MFMA16(qf0, *(const bf16x8*)(lds_k + key * 128 + c0 * 16), a, 0, 0, 0);
    a = MFMA16(qf1, *(const bf16x8*)(lds_k + key * 128 + c1 * 16), a, 0, 0, 0);
    acc_s[cf] = a;
  }
#pragma unroll
  for (int cf = 0; cf < 8; ++cf) {
    int kl = cf * 16 + (lane & 15);
#pragma unroll
    for (int r = 0; r < 4; ++r) {
      int qw = 4 * (lane >> 4) + r;
      float t = tst[qw * TW + (qw - kl + 127)];
      float vv = (acc_s[cf][r] + t) * 0.125f;
      if (j0 + kl > i0 + wv * 16 + qw) vv = MASKV;
      acc_s[cf][r] = vv;
    }
  }
}

__global__ __launch_bounds__(256, 2)
void attn_kernel(const bf16* __restrict__ qh, const bf16* __restrict__ kh,
                 const bf16* __restrict__ vt, const bf16* __restrict__ Ebf,
                 float* __restrict__ attn_out, bf16* __restrict__ oh)
{
  __shared__ __align__(16) char lds_k[128 * 128];      // [key][chunk^(key&7)] 16B chunks
  __shared__ __align__(16) char lds_v[64 * 256];       // [dh][chunk^(dh&7)]
  __shared__ __align__(16) char lds_t[4 * 16 * TW * 4]; // per-wave T strip / P strip alias

  const int tid = threadIdx.x, lane = tid & 63, wv = tid >> 6;
  const int qt = (int)gridDim.x - 1 - (int)blockIdx.x;  // heavy tiles first
  const int i0 = qt * BQ;
  const int bh = blockIdx.y;
  const bf16* qb = qh + (size_t)bh * Lq * 64;
  const bf16* kb = kh + (size_t)bh * Lq * 64;
  const bf16* vb = vt + (size_t)bh * 64 * Lq;
  float* attn_b = attn_out + (size_t)bh * Lq * Lq;
  float* tst = (float*)(lds_t + wv * (16 * TW * 4));
  bf16*  pst = (bf16*)(lds_t + wv * (16 * TW * 4));

  const int qrow = i0 + wv * 16 + (lane & 15);
  const bf16x8 qf0 = *(const bf16x8*)(qb + (size_t)qrow * 64 + (lane >> 4) * 8);
  const bf16x8 qf1 = *(const bf16x8*)(qb + (size_t)qrow * 64 + 32 + (lane >> 4) * 8);

  float m_run[4], s_run[4];
#pragma unroll
  for (int r = 0; r < 4; ++r) { m_run[r] = MASKV; s_run[r] = 0.f; }

  const int njt = (i0 + BQ - 1) / BKt + 1;
  f32x4 acc_s[8];

  // ---- PASS 1: online row max + sum (no writes) ----
  for (int jt = 0; jt < njt; ++jt) {
    const int j0 = jt * BKt;
    __syncthreads();
#pragma unroll
    for (int it = 0; it < 4; ++it) {
      int slot = it * 256 + wv * 64 + lane;
      int key = slot >> 3, c = slot & 7;
      async_load16(kb + (size_t)(j0 + key) * 64 + ((c ^ (key & 7)) * 8),
                   lds_k + (it * 256 + wv * 64) * 16);
    }
    __syncthreads();
    attn_logits(i0, j0, wv, lane, qf0, qf1, Ebf, lds_k, tst, acc_s);
#pragma unroll
    for (int r = 0; r < 4; ++r) {
      float mx = MASKV;
#pragma unroll
      for (int cf = 0; cf < 8; ++cf) mx = fmaxf(mx, acc_s[cf][r]);
      for (int d = 1; d < 16; d <<= 1) mx = fmaxf(mx, __shfl_xor(mx, d));
      float mnew = fmaxf(m_run[r], mx);
      float ps = 0.f;
#pragma unroll
      for (int cf = 0; cf < 8; ++cf) ps += __expf(acc_s[cf][r] - mnew);
      for (int d = 1; d < 16; d <<= 1) ps += __shfl_xor(ps, d);
      s_run[r] = s_run[r] * __expf(m_run[r] - mnew) + ps;
      m_run[r] = mnew;
    }
  }

  float inv_s[4];
#pragma unroll
  for (int r = 0; r < 4; ++r) inv_s[r] = 1.f / s_run[r];
  f32x4 acc_o[4];
#pragma unroll
  for (int n = 0; n < 4; ++n) acc_o[n] = (f32x4){0.f, 0.f, 0.f, 0.f};

  // ---- PASS 2: recompute, write attn, accumulate O = P.V ----
  for (int jt = 0; jt < Lq / BKt; ++jt) {
    const int j0 = jt * BKt;
    if (j0 >= i0 + BQ) {          // fully masked tile -> zeros
#pragma unroll
      for (int it = 0; it < 4; ++it) {
        int qw = it * 4 + (lane >> 4);
        float* dst = attn_b + (size_t)(i0 + wv * 16 + qw) * Lq + j0 + (lane & 15) * 8;
        *(float4*)dst = make_float4(0.f, 0.f, 0.f, 0.f);
        *(float4*)(dst + 4) = make_float4(0.f, 0.f, 0.f, 0.f);
      }
      continue;
    }
    __syncthreads();
#pragma unroll
    for (int it = 0; it < 4; ++it) {
      int slot = it * 256 + wv * 64 + lane;
      int key = slot >> 3, c = slot & 7;
      async_load16(kb + (size_t)(j0 + key) * 64 + ((c ^ (key & 7)) * 8),
                   lds_k + (it * 256 + wv * 64) * 16);
      int dh = slot >> 4, cv = slot & 15;
      async_load16(vb + (size_t)dh * Lq + j0 + ((cv ^ (dh & 7)) * 8),
                   lds_v + (it * 256 + wv * 64) * 16);
    }
    __syncthreads();
    attn_logits(i0, j0, wv, lane, qf0, qf1, Ebf, lds_k, tst, acc_s);
    asm volatile("" ::: "memory");   // keep P stores below T gathers (TBAA fence)
    // P strip (bf16, swizzled), aliases the (now dead) T strip
#pragma unroll
    for (int cf = 0; cf < 8; ++cf) {
      int kl = cf * 16 + (lane & 15);
      int chs = kl >> 3;
#pragma unroll
      for (int r = 0; r < 4; ++r) {
        int qw = 4 * (lane >> 4) + r;
        float p = __expf(acc_s[cf][r] - m_run[r]) * inv_s[r];
        pst[qw * 128 + ((chs ^ (qw & 7)) * 8) + (kl & 7)] = (bf16)p;
      }
    }
    asm volatile("s_waitcnt lgkmcnt(0)" ::: "memory");
    // attn write: full 512B rows from P strip
#pragma unroll
    for (int it = 0; it < 4; ++it) {
      int qw = it * 4 + (lane >> 4);
      int c = lane & 15;
      bf16x8 pv = *(const bf16x8*)(pst + qw * 128 + ((c ^ (qw & 7)) * 8));
      float* dst = attn_b + (size_t)(i0 + wv * 16 + qw) * Lq + j0 + c * 8;
      float4 f0, f1;
      f0.x = (float)pv[0]; f0.y = (float)pv[1]; f0.z = (float)pv[2]; f0.w = (float)pv[3];
      f1.x = (float)pv[4]; f1.y = (float)pv[5]; f1.z = (float)pv[6]; f1.w = (float)pv[7];
      *(float4*)dst = f0; *(float4*)(dst + 4) = f1;
    }
    // O += P.V
#pragma unroll
    for (int kc = 0; kc < 4; ++kc) {
      int qa = lane & 15;
      int cha = ((lane >> 4) + kc * 4) ^ (qa & 7);
      bf16x8 pf = *(const bf16x8*)(pst + qa * 128 + cha * 8);
#pragma unroll
      for (int n = 0; n < 4; ++n) {
        int dh = n * 16 + (lane & 15);
        int chv = ((lane >> 4) + kc * 4) ^ (dh & 7);
        bf16x8 vf = *(const bf16x8*)(lds_v + dh * 256 + chv * 16);
        acc_o[n] = MFMA16(pf, vf, acc_o[n], 0, 0, 0);
      }
    }
  }

  const int b = bh >> 3, h = bh & 7;
#pragma unroll
  for (int n = 0; n < 4; ++n)
#pragma unroll
    for (int r = 0; r < 4; ++r) {
      int qw = 4 * (lane >> 4) + r;
      int ig = i0 + wv * 16 + qw;
      int col = h * 64 + n * 16 + (lane & 15);
      oh[(size_t)(b * 2048 + ig) * 512 + col] = (bf16)acc_o[n][r];
    }
}

// ---------------------------------------------------------------------------
extern "C" void kernel_launch(void* const* d_in, const int* in_sizes, int n_in,
                              void* d_out, int out_size, void* d_ws, size_t ws_size,
                              hipStream_t stream) {
  const float* q    = (const float*)d_in[0];
  const float* k    = (const float*)d_in[1];
  const float* v    = (const float*)d_in[2];
  const float* wq   = (const float*)d_in[3];
  const float* wq_b = (const float*)d_in[4];
  const float* wk   = (const float*)d_in[5];
  const float* wk_b = (const float*)d_in[6];
  const float* wv   = (const float*)d_in[7];
  const float* wv_b = (const float*)d_in[8];
  const float* fc   = (const float*)d_in[9];
  const float* fc_b = (const float*)d_in[10];
  const float* E    = (const float*)d_in[11];

  if (ws_size < 31719424) return;  // workspace layout below needs ~30.3 MiB
  char* ws = (char*)d_ws;
  bf16* q_bf  = (bf16*)(ws);
  bf16* k_bf  = (bf16*)(ws + 4194304);
  bf16* v_bf  = (bf16*)(ws + 8388608);
  bf16* wq_bf = (bf16*)(ws + 12582912);
  bf16* wk_bf = (bf16*)(ws + 13107200);
  bf16* wv_bf = (bf16*)(ws + 13631488);
  bf16* fc_bf = (bf16*)(ws + 14155776);
  bf16* E_bf  = (bf16*)(ws + 14680064);
  bf16* qh_bf = (bf16*)(ws + 14942208);
  bf16* kh_bf = (bf16*)(ws + 19136512);
  bf16* vt_bf = (bf16*)(ws + 23330816);
  bf16* oh_bf = (bf16*)(ws + 27525120);

  float* out_f  = (float*)d_out;
  float* attn_f = out_f + 2097152;

  convert_all<<<7296, 256, 0, stream>>>(q, k, v, wq, wk, wv, fc, E,
      q_bf, k_bf, v_bf, wq_bf, wk_bf, wv_bf, fc_bf, E_bf);
  gemm512<0><<<dim3(32, 4), 256, 0, stream>>>(q_bf, wq_bf, wq_b, qh_bf);
  gemm512<0><<<dim3(32, 4), 256, 0, stream>>>(k_bf, wk_bf, wk_b, kh_bf);
  gemm512<2><<<dim3(4, 32), 256, 0, stream>>>(wv_bf, v_bf, wv_b, vt_bf);
  attn_kernel<<<dim3(32, 16), 256, 0, stream>>>(qh_bf, kh_bf, vt_bf, E_bf, attn_f, oh_bf);
  gemm512<3><<<dim3(32, 4), 256, 0, stream>>>(oh_bf, fc_bf, fc_b, out_f);
}